// Round 2
// baseline (1076.976 us; speedup 1.0000x reference)
//
#include <hip/hip_runtime.h>
#include <cstdint>

#define T_TOK 8192
#define Dm 1024
#define Fm 2048
#define Em 8

typedef unsigned short u16;
typedef __attribute__((ext_vector_type(8))) short short8;   // 8 bf16 (4 VGPRs)
typedef __attribute__((ext_vector_type(4))) float floatx4;  // MFMA C/D

__device__ __forceinline__ u16 f2bf(float f) {
  union { float f; unsigned u; } v; v.f = f;
  unsigned r = v.u + 0x7fffu + ((v.u >> 16) & 1u);  // RNE
  return (u16)(r >> 16);
}

__device__ __forceinline__ void gld_lds16(const void* g, void* l) {
  __builtin_amdgcn_global_load_lds(
      (const __attribute__((address_space(1))) void*)g,
      (__attribute__((address_space(3))) void*)l, 16, 0, 0);
}

// ---------------- zero metadata ----------------
__global__ void zero_meta(int* counts, int* offc, float* psum, float* zsum) {
  int t = threadIdx.x;
  if (t < 8) { counts[t] = 0; offc[t] = 0; psum[t] = 0.f; }
  if (t == 8) zsum[0] = 0.f;
}

// ---------------- all weights fp32 [E][R][C] -> bf16 transposed [E][C][R], one launch ----------------
__global__ __launch_bounds__(256) void transpose_all(
    const float* __restrict__ Wg, const float* __restrict__ Wu, const float* __restrict__ Wd,
    u16* __restrict__ WgT, u16* __restrict__ WuT, u16* __restrict__ WdT) {
  __shared__ u16 tile[64 * 66];
  int bid = blockIdx.x;
  int m = bid >> 9;        // matrix index 0..23 (512 tiles each)
  int t = bid & 511;
  int type = m >> 3, e = m & 7;
  const float* src; u16* dst; int R, C, csh;
  if (type == 0)      { src = Wg; dst = WgT; R = Dm; C = Fm; csh = 5; }
  else if (type == 1) { src = Wu; dst = WuT; R = Dm; C = Fm; csh = 5; }
  else                { src = Wd; dst = WdT; R = Fm; C = Dm; csh = 4; }
  int ty = t >> csh, tx = t & ((1 << csh) - 1);
  int r0 = ty * 64, c0 = tx * 64;
  const float* s = src + (size_t)e * R * C;
  u16* d = dst + (size_t)e * C * R;
  int tid = threadIdx.x;
#pragma unroll
  for (int p = 0; p < 16; ++p) {
    int idx = p * 256 + tid;
    int i = idx >> 6, j = idx & 63;
    tile[i * 66 + j] = f2bf(s[(size_t)(r0 + i) * C + (c0 + j)]);
  }
  __syncthreads();
#pragma unroll
  for (int p = 0; p < 16; ++p) {
    int idx = p * 256 + tid;
    int i = idx >> 6, j = idx & 63;
    d[(size_t)(c0 + i) * R + (r0 + j)] = tile[j * 66 + i];
  }
}

// ---------------- router: fp32 logits, softmax, top-2, aux partials; also emits x in bf16 ----------------
__global__ __launch_bounds__(256) void router_kernel(
    const float* __restrict__ x, const float* __restrict__ Wr,
    u16* __restrict__ xb,
    int* __restrict__ topi, float* __restrict__ topw,
    int* __restrict__ counts, float* __restrict__ psum, float* __restrict__ zsum) {
  __shared__ float wr_s[Dm * Em];  // 32KB
  __shared__ float redf[4][9];
  __shared__ int redi[4][8];
  int tid = threadIdx.x;
  for (int i = tid; i < Dm * Em; i += 256) wr_s[i] = Wr[i];
  __syncthreads();
  int wv = tid >> 6, lane = tid & 63;
  float pl[8] = {0, 0, 0, 0, 0, 0, 0, 0};
  float zl = 0.f;
  int cl[8] = {0, 0, 0, 0, 0, 0, 0, 0};
  for (int it = 0; it < 8; ++it) {
    int t = (blockIdx.x * 4 + wv) * 8 + it;
    const float* xt = x + (size_t)t * Dm;
    u16* xbt = xb + (size_t)t * Dm;
    float acc[8] = {0, 0, 0, 0, 0, 0, 0, 0};
#pragma unroll
    for (int i = 0; i < 16; ++i) {
      int dd = i * 64 + lane;
      float xv = xt[dd];
      xbt[dd] = f2bf(xv);
#pragma unroll
      for (int e2 = 0; e2 < 8; ++e2) acc[e2] += xv * wr_s[dd * 8 + e2];
    }
#pragma unroll
    for (int e2 = 0; e2 < 8; ++e2) {
      float v = acc[e2];
      for (int o = 32; o > 0; o >>= 1) v += __shfl_down(v, o);
      acc[e2] = v;
    }
    if (lane == 0) {
      float m = acc[0];
#pragma unroll
      for (int e2 = 1; e2 < 8; ++e2) m = fmaxf(m, acc[e2]);
      float p[8]; float s = 0.f;
#pragma unroll
      for (int e2 = 0; e2 < 8; ++e2) { p[e2] = expf(acc[e2] - m); s += p[e2]; }
      float inv = 1.f / s;
#pragma unroll
      for (int e2 = 0; e2 < 8; ++e2) { p[e2] *= inv; pl[e2] += p[e2]; }
      float lse = m + logf(s);
      zl += lse * lse;
      int i1 = 0;
#pragma unroll
      for (int e2 = 1; e2 < 8; ++e2) if (p[e2] > p[i1]) i1 = e2;  // strict > : low idx wins ties
      int i2 = -1; float b2 = -1e30f;
#pragma unroll
      for (int e2 = 0; e2 < 8; ++e2)
        if (e2 != i1 && p[e2] > b2) { b2 = p[e2]; i2 = e2; }
      float ssum = p[i1] + p[i2];
      topi[2 * t] = i1; topi[2 * t + 1] = i2;
      topw[2 * t] = p[i1] / ssum; topw[2 * t + 1] = p[i2] / ssum;
      cl[i1]++; cl[i2]++;
    }
  }
  if (lane == 0) {
#pragma unroll
    for (int e2 = 0; e2 < 8; ++e2) { redf[wv][e2] = pl[e2]; redi[wv][e2] = cl[e2]; }
    redf[wv][8] = zl;
  }
  __syncthreads();
  if (tid < 8) {
    atomicAdd(&psum[tid], redf[0][tid] + redf[1][tid] + redf[2][tid] + redf[3][tid]);
    atomicAdd(&counts[tid], redi[0][tid] + redi[1][tid] + redi[2][tid] + redi[3][tid]);
  } else if (tid == 8) {
    atomicAdd(zsum, redf[0][8] + redf[1][8] + redf[2][8] + redf[3][8]);
  }
}

// ---------------- finalize: prefix bases + aux loss ----------------
__global__ void finalize_kernel(const int* counts, const float* psum, const float* zsum,
                                int* bases, float* out_aux) {
  if (threadIdx.x == 0) {
    int b = 0;
    for (int e = 0; e < 8; ++e) { bases[e] = b; b += counts[e]; }
    bases[8] = b;
    float lb = 0.f;
    for (int e = 0; e < 8; ++e)
      lb += ((float)counts[e] / (2.f * T_TOK)) * (psum[e] / (float)T_TOK);
    lb *= 8.f;
    float z = zsum[0] / (float)T_TOK;
    *out_aux = 0.01f * lb + 0.001f * z;
  }
}

// ---------------- scatter: compact token lists per expert ----------------
__global__ __launch_bounds__(256) void scatter_kernel(
    const int* __restrict__ topi, const float* __restrict__ topw,
    const int* __restrict__ bases, int* __restrict__ offc,
    int* __restrict__ etok, float* __restrict__ ew) {
  __shared__ int lcnt[8];
  __shared__ int lbase[8];
  int tid = threadIdx.x;
  if (tid < 8) lcnt[tid] = 0;
  __syncthreads();
  int t = blockIdx.x * 256 + tid;
  int e0 = topi[2 * t], e1 = topi[2 * t + 1];
  int lp0 = atomicAdd(&lcnt[e0], 1);
  int lp1 = atomicAdd(&lcnt[e1], 1);
  __syncthreads();
  if (tid < 8) lbase[tid] = atomicAdd(&offc[tid], lcnt[tid]);
  __syncthreads();
  int p0 = bases[e0] + lbase[e0] + lp0;
  etok[p0] = t; ew[p0] = topw[2 * t];
  int p1 = bases[e1] + lbase[e1] + lp1;
  etok[p1] = t; ew[p1] = topw[2 * t + 1];
}

// ---------------- GEMM1: h = silu(X@Wg) * (X@Wu), gathered rows, bf16 MFMA ----------------
// launch_bounds(256,3): 3 blocks/CU (LDS 48KB*3=144KB<=160KB, VGPR 108<=170) — occupancy was the
// round-1 limiter (20%, only ~1.6 blocks/CU to hide the barrier drain).
__global__ __launch_bounds__(256, 3) void gemm1_kernel(
    const u16* __restrict__ xb, const u16* __restrict__ WgT, const u16* __restrict__ WuT,
    u16* __restrict__ h, const int* __restrict__ etok,
    const int* __restrict__ counts, const int* __restrict__ bases) {
  const int e = blockIdx.z;
  const int Ne = counts[e];
  const int m0 = blockIdx.y * 128;
  if (m0 >= Ne) return;
  const int n0 = blockIdx.x * 128;
  const int be = bases[e];

  __shared__ __align__(16) u16 As[128 * 64];
  __shared__ __align__(16) u16 Bgs[128 * 64];
  __shared__ __align__(16) u16 Bus[128 * 64];

  const int tid = threadIdx.x;
  const int wv = tid >> 6, lane = tid & 63;
  const int wr = wv >> 1, wc = wv & 1;

  const int srow = tid >> 3;                    // 0..31
  const int cg = (tid & 7) ^ (srow & 7);        // xor-swizzled global chunk
  const u16* wg_e = WgT + (size_t)e * Fm * Dm;  // [F][D], k-contig
  const u16* wu_e = WuT + (size_t)e * Fm * Dm;

  const u16* ag[4]; const u16* bgp[4]; const u16* bup[4];
#pragma unroll
  for (int j = 0; j < 4; ++j) {
    int row = 32 * j + srow;
    int rr = m0 + row; rr = rr < Ne ? rr : Ne - 1;
    int tok = etok[be + rr];
    ag[j] = xb + (size_t)tok * Dm + cg * 8;
    bgp[j] = wg_e + (size_t)(n0 + row) * Dm + cg * 8;
    bup[j] = wu_e + (size_t)(n0 + row) * Dm + cg * 8;
  }
  const int lbase = 8 * wv * 64 + lane * 8;  // forced lane layout (base + 16B*lane)

  floatx4 accg[4][4], accu[4][4];
#pragma unroll
  for (int mi = 0; mi < 4; ++mi)
#pragma unroll
    for (int ni = 0; ni < 4; ++ni) { accg[mi][ni] = (floatx4)0.f; accu[mi][ni] = (floatx4)0.f; }

  for (int k0 = 0; k0 < Dm; k0 += 64) {
    __syncthreads();
#pragma unroll
    for (int j = 0; j < 4; ++j) {
      int lo = lbase + 32 * j * 64;
      gld_lds16(ag[j] + k0, &As[lo]);
      gld_lds16(bgp[j] + k0, &Bgs[lo]);
      gld_lds16(bup[j] + k0, &Bus[lo]);
    }
    __syncthreads();
#pragma unroll
    for (int ks = 0; ks < 2; ++ks) {
      short8 af[4], bgf[4], buf_[4];
      const int col = lane & 15, quad = lane >> 4;
      const int c = ks * 4 + quad;
#pragma unroll
      for (int mi = 0; mi < 4; ++mi) {
        int row = wr * 64 + mi * 16 + col;
        af[mi] = *(const short8*)&As[row * 64 + ((c ^ (row & 7)) << 3)];
      }
#pragma unroll
      for (int ni = 0; ni < 4; ++ni) {
        int row = wc * 64 + ni * 16 + col;
        int o = row * 64 + ((c ^ (row & 7)) << 3);
        bgf[ni] = *(const short8*)&Bgs[o];
        buf_[ni] = *(const short8*)&Bus[o];
      }
#pragma unroll
      for (int mi = 0; mi < 4; ++mi)
#pragma unroll
        for (int ni = 0; ni < 4; ++ni) {
          accg[mi][ni] = __builtin_amdgcn_mfma_f32_16x16x32_bf16(af[mi], bgf[ni], accg[mi][ni], 0, 0, 0);
          accu[mi][ni] = __builtin_amdgcn_mfma_f32_16x16x32_bf16(af[mi], buf_[ni], accu[mi][ni], 0, 0, 0);
        }
    }
  }
  const int col = lane & 15, quad = lane >> 4;
#pragma unroll
  for (int mi = 0; mi < 4; ++mi)
#pragma unroll
    for (int ni = 0; ni < 4; ++ni) {
      int f = n0 + wc * 64 + ni * 16 + col;
#pragma unroll
      for (int r = 0; r < 4; ++r) {
        int lrow = wr * 64 + mi * 16 + quad * 4 + r;
        if (m0 + lrow < Ne) {
          float gv = accg[mi][ni][r];
          float hv = (gv / (1.f + expf(-gv))) * accu[mi][ni][r];
          h[(size_t)(be + m0 + lrow) * Fm + f] = f2bf(hv);
        }
      }
    }
}

// ---------------- GEMM2: out += w * (h @ Wd), scatter via atomics ----------------
// launch_bounds(256,4): 4 blocks/CU (LDS ~33KB*4=132KB<=160KB, VGPR cap 128).
__global__ __launch_bounds__(256, 4) void gemm2_kernel(
    const u16* __restrict__ h, const u16* __restrict__ WdT, float* __restrict__ out,
    const int* __restrict__ etok, const float* __restrict__ ew,
    const int* __restrict__ counts, const int* __restrict__ bases) {
  const int e = blockIdx.z;
  const int Ne = counts[e];
  const int m0 = blockIdx.y * 128;
  if (m0 >= Ne) return;
  const int n0 = blockIdx.x * 128;
  const int be = bases[e];

  __shared__ __align__(16) u16 As[128 * 64];
  __shared__ __align__(16) u16 Bs[128 * 64];
  __shared__ int tokS[128];
  __shared__ float wS[128];

  const int tid = threadIdx.x;
  if (tid < 128) {
    int rr = m0 + tid; rr = rr < Ne ? rr : Ne - 1;
    tokS[tid] = etok[be + rr];
    wS[tid] = ew[be + rr];
  }
  const int wv = tid >> 6, lane = tid & 63;
  const int wr = wv >> 1, wc = wv & 1;
  const int srow = tid >> 3;
  const int cg = (tid & 7) ^ (srow & 7);
  const u16* wd_e = WdT + (size_t)e * Dm * Fm;  // [D][F], k-contig

  const u16* ap[4]; const u16* bp[4];
#pragma unroll
  for (int j = 0; j < 4; ++j) {
    int row = 32 * j + srow;
    int rr = m0 + row; rr = rr < Ne ? rr : Ne - 1;
    ap[j] = h + (size_t)(be + rr) * Fm + cg * 8;
    bp[j] = wd_e + (size_t)(n0 + row) * Fm + cg * 8;
  }
  const int lbase = 8 * wv * 64 + lane * 8;

  floatx4 acc[4][4];
#pragma unroll
  for (int mi = 0; mi < 4; ++mi)
#pragma unroll
    for (int ni = 0; ni < 4; ++ni) acc[mi][ni] = (floatx4)0.f;

  for (int k0 = 0; k0 < Fm; k0 += 64) {
    __syncthreads();
#pragma unroll
    for (int j = 0; j < 4; ++j) {
      int lo = lbase + 32 * j * 64;
      gld_lds16(ap[j] + k0, &As[lo]);
      gld_lds16(bp[j] + k0, &Bs[lo]);
    }
    __syncthreads();
#pragma unroll
    for (int ks = 0; ks < 2; ++ks) {
      short8 af[4], bf[4];
      const int col = lane & 15, quad = lane >> 4;
      const int c = ks * 4 + quad;
#pragma unroll
      for (int mi = 0; mi < 4; ++mi) {
        int row = wr * 64 + mi * 16 + col;
        af[mi] = *(const short8*)&As[row * 64 + ((c ^ (row & 7)) << 3)];
      }
#pragma unroll
      for (int ni = 0; ni < 4; ++ni) {
        int row = wc * 64 + ni * 16 + col;
        bf[ni] = *(const short8*)&Bs[row * 64 + ((c ^ (row & 7)) << 3)];
      }
#pragma unroll
      for (int mi = 0; mi < 4; ++mi)
#pragma unroll
        for (int ni = 0; ni < 4; ++ni)
          acc[mi][ni] = __builtin_amdgcn_mfma_f32_16x16x32_bf16(af[mi], bf[ni], acc[mi][ni], 0, 0, 0);
    }
  }
  const int col = lane & 15, quad = lane >> 4;
#pragma unroll
  for (int mi = 0; mi < 4; ++mi)
#pragma unroll
    for (int ni = 0; ni < 4; ++ni) {
      int oc = n0 + wc * 64 + ni * 16 + col;
#pragma unroll
      for (int r = 0; r < 4; ++r) {
        int lrow = wr * 64 + mi * 16 + quad * 4 + r;
        if (m0 + lrow < Ne) {
          float v = acc[mi][ni][r] * wS[lrow];
          atomicAdd(&out[(size_t)tokS[lrow] * Dm + oc], v);
        }
      }
    }
}

extern "C" void kernel_launch(void* const* d_in, const int* in_sizes, int n_in,
                              void* d_out, int out_size, void* d_ws, size_t ws_size,
                              hipStream_t stream) {
  const float* x = (const float*)d_in[0];
  const float* Wr = (const float*)d_in[1];
  const float* Wg = (const float*)d_in[2];
  const float* Wu = (const float*)d_in[3];
  const float* Wd = (const float*)d_in[4];
  float* out = (float*)d_out;

  char* p = (char*)d_ws;
  auto take = [&](size_t bytes) { char* r = p; p += (bytes + 255) & ~(size_t)255; return r; };
  u16* xb = (u16*)take((size_t)T_TOK * Dm * 2);
  u16* WgT = (u16*)take((size_t)Em * Fm * Dm * 2);
  u16* WuT = (u16*)take((size_t)Em * Fm * Dm * 2);
  u16* WdT = (u16*)take((size_t)Em * Dm * Fm * 2);
  u16* h = (u16*)take((size_t)2 * T_TOK * Fm * 2);
  int* topi = (int*)take((size_t)T_TOK * 2 * 4);
  float* topw = (float*)take((size_t)T_TOK * 2 * 4);
  int* etok = (int*)take((size_t)2 * T_TOK * 4);
  float* ew = (float*)take((size_t)2 * T_TOK * 4);
  int* counts = (int*)take(64);
  int* bases = (int*)take(64);
  int* offc = (int*)take(64);
  float* psum = (float*)take(64);
  float* zsum = (float*)take(64);

  hipMemsetAsync(d_out, 0, (size_t)out_size * 4, stream);
  zero_meta<<<1, 64, 0, stream>>>(counts, offc, psum, zsum);
  transpose_all<<<dim3(24 * 512), 256, 0, stream>>>(Wg, Wu, Wd, WgT, WuT, WdT);
  router_kernel<<<dim3(T_TOK / 32), 256, 0, stream>>>(x, Wr, xb, topi, topw, counts, psum, zsum);
  finalize_kernel<<<1, 64, 0, stream>>>(counts, psum, zsum, bases, out + (size_t)T_TOK * Dm);
  scatter_kernel<<<dim3(T_TOK / 256), 256, 0, stream>>>(topi, topw, bases, offc, etok, ew);
  gemm1_kernel<<<dim3(Fm / 128, 64, Em), 256, 0, stream>>>(xb, WgT, WuT, h, etok, counts, bases);
  gemm2_kernel<<<dim3(Dm / 128, 64, Em), 256, 0, stream>>>(h, WdT, out, etok, ew, counts, bases);
}

// Round 3
// 637.225 us; speedup vs baseline: 1.6901x; 1.6901x over previous
//
#include <hip/hip_runtime.h>
#include <cstdint>

#define T_TOK 8192
#define Dm 1024
#define Fm 2048
#define Em 8

typedef unsigned short u16;
typedef __attribute__((ext_vector_type(8))) short short8;   // 8 bf16 (4 VGPRs)
typedef __attribute__((ext_vector_type(4))) float floatx4;  // MFMA C/D

__device__ __forceinline__ u16 f2bf(float f) {
  union { float f; unsigned u; } v; v.f = f;
  unsigned r = v.u + 0x7fffu + ((v.u >> 16) & 1u);  // RNE
  return (u16)(r >> 16);
}
__device__ __forceinline__ float bf2f(u16 b) {
  union { unsigned u; float f; } v; v.u = ((unsigned)b) << 16; return v.f;
}

__device__ __forceinline__ void gld_lds16(const void* g, void* l) {
  __builtin_amdgcn_global_load_lds(
      (const __attribute__((address_space(1))) void*)g,
      (__attribute__((address_space(3))) void*)l, 16, 0, 0);
}

// ---------------- zero metadata ----------------
__global__ void zero_meta(int* counts, int* offc, float* psum, float* zsum) {
  int t = threadIdx.x;
  if (t < 8) { counts[t] = 0; offc[t] = 0; psum[t] = 0.f; }
  if (t == 8) zsum[0] = 0.f;
}

// ---------------- all weights fp32 [E][R][C] -> bf16 transposed [E][C][R], one launch ----------------
__global__ __launch_bounds__(256) void transpose_all(
    const float* __restrict__ Wg, const float* __restrict__ Wu, const float* __restrict__ Wd,
    u16* __restrict__ WgT, u16* __restrict__ WuT, u16* __restrict__ WdT) {
  __shared__ u16 tile[64 * 66];
  int bid = blockIdx.x;
  int m = bid >> 9;        // matrix index 0..23 (512 tiles each)
  int t = bid & 511;
  int type = m >> 3, e = m & 7;
  const float* src; u16* dst; int R, C, csh;
  if (type == 0)      { src = Wg; dst = WgT; R = Dm; C = Fm; csh = 5; }
  else if (type == 1) { src = Wu; dst = WuT; R = Dm; C = Fm; csh = 5; }
  else                { src = Wd; dst = WdT; R = Fm; C = Dm; csh = 4; }
  int ty = t >> csh, tx = t & ((1 << csh) - 1);
  int r0 = ty * 64, c0 = tx * 64;
  const float* s = src + (size_t)e * R * C;
  u16* d = dst + (size_t)e * C * R;
  int tid = threadIdx.x;
#pragma unroll
  for (int p = 0; p < 16; ++p) {
    int idx = p * 256 + tid;
    int i = idx >> 6, j = idx & 63;
    tile[i * 66 + j] = f2bf(s[(size_t)(r0 + i) * C + (c0 + j)]);
  }
  __syncthreads();
#pragma unroll
  for (int p = 0; p < 16; ++p) {
    int idx = p * 256 + tid;
    int i = idx >> 6, j = idx & 63;
    d[(size_t)(c0 + i) * R + (r0 + j)] = tile[j * 66 + i];
  }
}

// ---------------- router: fp32 logits, softmax, top-2, aux partials; also emits x in bf16 ----------------
__global__ __launch_bounds__(256) void router_kernel(
    const float* __restrict__ x, const float* __restrict__ Wr,
    u16* __restrict__ xb,
    int* __restrict__ topi, float* __restrict__ topw,
    int* __restrict__ counts, float* __restrict__ psum, float* __restrict__ zsum) {
  __shared__ float wr_s[Dm * Em];  // 32KB
  __shared__ float redf[4][9];
  __shared__ int redi[4][8];
  int tid = threadIdx.x;
  for (int i = tid; i < Dm * Em; i += 256) wr_s[i] = Wr[i];
  __syncthreads();
  int wv = tid >> 6, lane = tid & 63;
  float pl[8] = {0, 0, 0, 0, 0, 0, 0, 0};
  float zl = 0.f;
  int cl[8] = {0, 0, 0, 0, 0, 0, 0, 0};
  for (int it = 0; it < 8; ++it) {
    int t = (blockIdx.x * 4 + wv) * 8 + it;
    const float* xt = x + (size_t)t * Dm;
    u16* xbt = xb + (size_t)t * Dm;
    float acc[8] = {0, 0, 0, 0, 0, 0, 0, 0};
#pragma unroll
    for (int i = 0; i < 16; ++i) {
      int dd = i * 64 + lane;
      float xv = xt[dd];
      xbt[dd] = f2bf(xv);
#pragma unroll
      for (int e2 = 0; e2 < 8; ++e2) acc[e2] += xv * wr_s[dd * 8 + e2];
    }
#pragma unroll
    for (int e2 = 0; e2 < 8; ++e2) {
      float v = acc[e2];
      for (int o = 32; o > 0; o >>= 1) v += __shfl_down(v, o);
      acc[e2] = v;
    }
    if (lane == 0) {
      float m = acc[0];
#pragma unroll
      for (int e2 = 1; e2 < 8; ++e2) m = fmaxf(m, acc[e2]);
      float p[8]; float s = 0.f;
#pragma unroll
      for (int e2 = 0; e2 < 8; ++e2) { p[e2] = expf(acc[e2] - m); s += p[e2]; }
      float inv = 1.f / s;
#pragma unroll
      for (int e2 = 0; e2 < 8; ++e2) { p[e2] *= inv; pl[e2] += p[e2]; }
      float lse = m + logf(s);
      zl += lse * lse;
      int i1 = 0;
#pragma unroll
      for (int e2 = 1; e2 < 8; ++e2) if (p[e2] > p[i1]) i1 = e2;  // strict > : low idx wins ties
      int i2 = -1; float b2 = -1e30f;
#pragma unroll
      for (int e2 = 0; e2 < 8; ++e2)
        if (e2 != i1 && p[e2] > b2) { b2 = p[e2]; i2 = e2; }
      float ssum = p[i1] + p[i2];
      topi[2 * t] = i1; topi[2 * t + 1] = i2;
      topw[2 * t] = p[i1] / ssum; topw[2 * t + 1] = p[i2] / ssum;
      cl[i1]++; cl[i2]++;
    }
  }
  if (lane == 0) {
#pragma unroll
    for (int e2 = 0; e2 < 8; ++e2) { redf[wv][e2] = pl[e2]; redi[wv][e2] = cl[e2]; }
    redf[wv][8] = zl;
  }
  __syncthreads();
  if (tid < 8) {
    atomicAdd(&psum[tid], redf[0][tid] + redf[1][tid] + redf[2][tid] + redf[3][tid]);
    atomicAdd(&counts[tid], redi[0][tid] + redi[1][tid] + redi[2][tid] + redi[3][tid]);
  } else if (tid == 8) {
    atomicAdd(zsum, redf[0][8] + redf[1][8] + redf[2][8] + redf[3][8]);
  }
}

// ---------------- finalize: prefix bases + aux loss ----------------
__global__ void finalize_kernel(const int* counts, const float* psum, const float* zsum,
                                int* bases, float* out_aux) {
  if (threadIdx.x == 0) {
    int b = 0;
    for (int e = 0; e < 8; ++e) { bases[e] = b; b += counts[e]; }
    bases[8] = b;
    float lb = 0.f;
    for (int e = 0; e < 8; ++e)
      lb += ((float)counts[e] / (2.f * T_TOK)) * (psum[e] / (float)T_TOK);
    lb *= 8.f;
    float z = zsum[0] / (float)T_TOK;
    *out_aux = 0.01f * lb + 0.001f * z;
  }
}

// ---------------- scatter: compact token lists per expert ----------------
__global__ __launch_bounds__(256) void scatter_kernel(
    const int* __restrict__ topi, const float* __restrict__ topw,
    const int* __restrict__ bases, int* __restrict__ offc,
    int* __restrict__ etok, float* __restrict__ ew) {
  __shared__ int lcnt[8];
  __shared__ int lbase[8];
  int tid = threadIdx.x;
  if (tid < 8) lcnt[tid] = 0;
  __syncthreads();
  int t = blockIdx.x * 256 + tid;
  int e0 = topi[2 * t], e1 = topi[2 * t + 1];
  int lp0 = atomicAdd(&lcnt[e0], 1);
  int lp1 = atomicAdd(&lcnt[e1], 1);
  __syncthreads();
  if (tid < 8) lbase[tid] = atomicAdd(&offc[tid], lcnt[tid]);
  __syncthreads();
  int p0 = bases[e0] + lbase[e0] + lp0;
  etok[p0] = t; ew[p0] = topw[2 * t];
  int p1 = bases[e1] + lbase[e1] + lp1;
  etok[p1] = t; ew[p1] = topw[2 * t + 1];
}

// ---------------- GEMM-G: g = X@WgT (gathered rows), bf16 out ----------------
// m97-shape: 32KB LDS, 64 acc regs, launch_bounds(256,2) — (256,3) spilled acc in round 2.
__global__ __launch_bounds__(256, 2) void gemm_g_kernel(
    const u16* __restrict__ xb, const u16* __restrict__ WgT,
    u16* __restrict__ gh, const int* __restrict__ etok,
    const int* __restrict__ counts, const int* __restrict__ bases) {
  const int e = blockIdx.z;
  const int Ne = counts[e];
  const int m0 = blockIdx.y * 128;
  if (m0 >= Ne) return;
  const int n0 = blockIdx.x * 128;
  const int be = bases[e];

  __shared__ __align__(16) u16 As[128 * 64];
  __shared__ __align__(16) u16 Bs[128 * 64];

  const int tid = threadIdx.x;
  const int wv = tid >> 6, lane = tid & 63;
  const int wr = wv >> 1, wc = wv & 1;
  const int srow = tid >> 3;
  const int cg = (tid & 7) ^ (srow & 7);
  const u16* wg_e = WgT + (size_t)e * Fm * Dm;  // [F][D], k-contig

  const u16* ap[4]; const u16* bp[4];
#pragma unroll
  for (int j = 0; j < 4; ++j) {
    int row = 32 * j + srow;
    int rr = m0 + row; rr = rr < Ne ? rr : Ne - 1;
    int tok = etok[be + rr];
    ap[j] = xb + (size_t)tok * Dm + cg * 8;
    bp[j] = wg_e + (size_t)(n0 + row) * Dm + cg * 8;
  }
  const int lbase = 8 * wv * 64 + lane * 8;

  floatx4 acc[4][4];
#pragma unroll
  for (int mi = 0; mi < 4; ++mi)
#pragma unroll
    for (int ni = 0; ni < 4; ++ni) acc[mi][ni] = (floatx4)0.f;

  for (int k0 = 0; k0 < Dm; k0 += 64) {
    __syncthreads();
#pragma unroll
    for (int j = 0; j < 4; ++j) {
      int lo = lbase + 32 * j * 64;
      gld_lds16(ap[j] + k0, &As[lo]);
      gld_lds16(bp[j] + k0, &Bs[lo]);
    }
    __syncthreads();
#pragma unroll
    for (int ks = 0; ks < 2; ++ks) {
      short8 af[4], bf[4];
      const int col = lane & 15, quad = lane >> 4;
      const int c = ks * 4 + quad;
#pragma unroll
      for (int mi = 0; mi < 4; ++mi) {
        int row = wr * 64 + mi * 16 + col;
        af[mi] = *(const short8*)&As[row * 64 + ((c ^ (row & 7)) << 3)];
      }
#pragma unroll
      for (int ni = 0; ni < 4; ++ni) {
        int row = wc * 64 + ni * 16 + col;
        bf[ni] = *(const short8*)&Bs[row * 64 + ((c ^ (row & 7)) << 3)];
      }
#pragma unroll
      for (int mi = 0; mi < 4; ++mi)
#pragma unroll
        for (int ni = 0; ni < 4; ++ni)
          acc[mi][ni] = __builtin_amdgcn_mfma_f32_16x16x32_bf16(af[mi], bf[ni], acc[mi][ni], 0, 0, 0);
    }
  }
  const int col = lane & 15, quad = lane >> 4;
#pragma unroll
  for (int mi = 0; mi < 4; ++mi)
#pragma unroll
    for (int ni = 0; ni < 4; ++ni) {
      int f = n0 + wc * 64 + ni * 16 + col;
#pragma unroll
      for (int r = 0; r < 4; ++r) {
        int lrow = wr * 64 + mi * 16 + quad * 4 + r;
        if (m0 + lrow < Ne)
          gh[(size_t)(be + m0 + lrow) * Fm + f] = f2bf(acc[mi][ni][r]);
      }
    }
}

// ---------------- GEMM-U: u = X@WuT; epilogue h = silu(g)*u written IN PLACE over g ----------------
__global__ __launch_bounds__(256, 2) void gemm_u_kernel(
    const u16* __restrict__ xb, const u16* __restrict__ WuT,
    u16* __restrict__ gh, const int* __restrict__ etok,
    const int* __restrict__ counts, const int* __restrict__ bases) {
  const int e = blockIdx.z;
  const int Ne = counts[e];
  const int m0 = blockIdx.y * 128;
  if (m0 >= Ne) return;
  const int n0 = blockIdx.x * 128;
  const int be = bases[e];

  __shared__ __align__(16) u16 As[128 * 64];
  __shared__ __align__(16) u16 Bs[128 * 64];

  const int tid = threadIdx.x;
  const int wv = tid >> 6, lane = tid & 63;
  const int wr = wv >> 1, wc = wv & 1;
  const int srow = tid >> 3;
  const int cg = (tid & 7) ^ (srow & 7);
  const u16* wu_e = WuT + (size_t)e * Fm * Dm;

  const u16* ap[4]; const u16* bp[4];
#pragma unroll
  for (int j = 0; j < 4; ++j) {
    int row = 32 * j + srow;
    int rr = m0 + row; rr = rr < Ne ? rr : Ne - 1;
    int tok = etok[be + rr];
    ap[j] = xb + (size_t)tok * Dm + cg * 8;
    bp[j] = wu_e + (size_t)(n0 + row) * Dm + cg * 8;
  }
  const int lbase = 8 * wv * 64 + lane * 8;

  floatx4 acc[4][4];
#pragma unroll
  for (int mi = 0; mi < 4; ++mi)
#pragma unroll
    for (int ni = 0; ni < 4; ++ni) acc[mi][ni] = (floatx4)0.f;

  for (int k0 = 0; k0 < Dm; k0 += 64) {
    __syncthreads();
#pragma unroll
    for (int j = 0; j < 4; ++j) {
      int lo = lbase + 32 * j * 64;
      gld_lds16(ap[j] + k0, &As[lo]);
      gld_lds16(bp[j] + k0, &Bs[lo]);
    }
    __syncthreads();
#pragma unroll
    for (int ks = 0; ks < 2; ++ks) {
      short8 af[4], bf[4];
      const int col = lane & 15, quad = lane >> 4;
      const int c = ks * 4 + quad;
#pragma unroll
      for (int mi = 0; mi < 4; ++mi) {
        int row = wr * 64 + mi * 16 + col;
        af[mi] = *(const short8*)&As[row * 64 + ((c ^ (row & 7)) << 3)];
      }
#pragma unroll
      for (int ni = 0; ni < 4; ++ni) {
        int row = wc * 64 + ni * 16 + col;
        bf[ni] = *(const short8*)&Bs[row * 64 + ((c ^ (row & 7)) << 3)];
      }
#pragma unroll
      for (int mi = 0; mi < 4; ++mi)
#pragma unroll
        for (int ni = 0; ni < 4; ++ni)
          acc[mi][ni] = __builtin_amdgcn_mfma_f32_16x16x32_bf16(af[mi], bf[ni], acc[mi][ni], 0, 0, 0);
    }
  }
  const int col = lane & 15, quad = lane >> 4;
#pragma unroll
  for (int mi = 0; mi < 4; ++mi)
#pragma unroll
    for (int ni = 0; ni < 4; ++ni) {
      int f = n0 + wc * 64 + ni * 16 + col;
#pragma unroll
      for (int r = 0; r < 4; ++r) {
        int lrow = wr * 64 + mi * 16 + quad * 4 + r;
        if (m0 + lrow < Ne) {
          size_t idx = (size_t)(be + m0 + lrow) * Fm + f;
          float gv = bf2f(gh[idx]);
          float hv = (gv / (1.f + expf(-gv))) * acc[mi][ni][r];
          gh[idx] = f2bf(hv);
        }
      }
    }
}

// ---------------- GEMM2: out += w * (h @ Wd), scatter via atomics ----------------
__global__ __launch_bounds__(256, 2) void gemm2_kernel(
    const u16* __restrict__ h, const u16* __restrict__ WdT, float* __restrict__ out,
    const int* __restrict__ etok, const float* __restrict__ ew,
    const int* __restrict__ counts, const int* __restrict__ bases) {
  const int e = blockIdx.z;
  const int Ne = counts[e];
  const int m0 = blockIdx.y * 128;
  if (m0 >= Ne) return;
  const int n0 = blockIdx.x * 128;
  const int be = bases[e];

  __shared__ __align__(16) u16 As[128 * 64];
  __shared__ __align__(16) u16 Bs[128 * 64];
  __shared__ int tokS[128];
  __shared__ float wS[128];

  const int tid = threadIdx.x;
  if (tid < 128) {
    int rr = m0 + tid; rr = rr < Ne ? rr : Ne - 1;
    tokS[tid] = etok[be + rr];
    wS[tid] = ew[be + rr];
  }
  const int wv = tid >> 6, lane = tid & 63;
  const int wr = wv >> 1, wc = wv & 1;
  const int srow = tid >> 3;
  const int cg = (tid & 7) ^ (srow & 7);
  const u16* wd_e = WdT + (size_t)e * Dm * Fm;  // [D][F], k-contig

  const u16* ap[4]; const u16* bp[4];
#pragma unroll
  for (int j = 0; j < 4; ++j) {
    int row = 32 * j + srow;
    int rr = m0 + row; rr = rr < Ne ? rr : Ne - 1;
    ap[j] = h + (size_t)(be + rr) * Fm + cg * 8;
    bp[j] = wd_e + (size_t)(n0 + row) * Fm + cg * 8;
  }
  const int lbase = 8 * wv * 64 + lane * 8;

  floatx4 acc[4][4];
#pragma unroll
  for (int mi = 0; mi < 4; ++mi)
#pragma unroll
    for (int ni = 0; ni < 4; ++ni) acc[mi][ni] = (floatx4)0.f;

  for (int k0 = 0; k0 < Fm; k0 += 64) {
    __syncthreads();
#pragma unroll
    for (int j = 0; j < 4; ++j) {
      int lo = lbase + 32 * j * 64;
      gld_lds16(ap[j] + k0, &As[lo]);
      gld_lds16(bp[j] + k0, &Bs[lo]);
    }
    __syncthreads();
#pragma unroll
    for (int ks = 0; ks < 2; ++ks) {
      short8 af[4], bf[4];
      const int col = lane & 15, quad = lane >> 4;
      const int c = ks * 4 + quad;
#pragma unroll
      for (int mi = 0; mi < 4; ++mi) {
        int row = wr * 64 + mi * 16 + col;
        af[mi] = *(const short8*)&As[row * 64 + ((c ^ (row & 7)) << 3)];
      }
#pragma unroll
      for (int ni = 0; ni < 4; ++ni) {
        int row = wc * 64 + ni * 16 + col;
        bf[ni] = *(const short8*)&Bs[row * 64 + ((c ^ (row & 7)) << 3)];
      }
#pragma unroll
      for (int mi = 0; mi < 4; ++mi)
#pragma unroll
        for (int ni = 0; ni < 4; ++ni)
          acc[mi][ni] = __builtin_amdgcn_mfma_f32_16x16x32_bf16(af[mi], bf[ni], acc[mi][ni], 0, 0, 0);
    }
  }
  const int col = lane & 15, quad = lane >> 4;
#pragma unroll
  for (int mi = 0; mi < 4; ++mi)
#pragma unroll
    for (int ni = 0; ni < 4; ++ni) {
      int oc = n0 + wc * 64 + ni * 16 + col;
#pragma unroll
      for (int r = 0; r < 4; ++r) {
        int lrow = wr * 64 + mi * 16 + quad * 4 + r;
        if (m0 + lrow < Ne) {
          float v = acc[mi][ni][r] * wS[lrow];
          atomicAdd(&out[(size_t)tokS[lrow] * Dm + oc], v);
        }
      }
    }
}

extern "C" void kernel_launch(void* const* d_in, const int* in_sizes, int n_in,
                              void* d_out, int out_size, void* d_ws, size_t ws_size,
                              hipStream_t stream) {
  const float* x = (const float*)d_in[0];
  const float* Wr = (const float*)d_in[1];
  const float* Wg = (const float*)d_in[2];
  const float* Wu = (const float*)d_in[3];
  const float* Wd = (const float*)d_in[4];
  float* out = (float*)d_out;

  char* p = (char*)d_ws;
  auto take = [&](size_t bytes) { char* r = p; p += (bytes + 255) & ~(size_t)255; return r; };
  u16* xb = (u16*)take((size_t)T_TOK * Dm * 2);
  u16* WgT = (u16*)take((size_t)Em * Fm * Dm * 2);
  u16* WuT = (u16*)take((size_t)Em * Fm * Dm * 2);
  u16* WdT = (u16*)take((size_t)Em * Dm * Fm * 2);
  u16* gh = (u16*)take((size_t)2 * T_TOK * Fm * 2);  // g, overwritten in place by h
  int* topi = (int*)take((size_t)T_TOK * 2 * 4);
  float* topw = (float*)take((size_t)T_TOK * 2 * 4);
  int* etok = (int*)take((size_t)2 * T_TOK * 4);
  float* ew = (float*)take((size_t)2 * T_TOK * 4);
  int* counts = (int*)take(64);
  int* bases = (int*)take(64);
  int* offc = (int*)take(64);
  float* psum = (float*)take(64);
  float* zsum = (float*)take(64);

  hipMemsetAsync(d_out, 0, (size_t)out_size * 4, stream);
  zero_meta<<<1, 64, 0, stream>>>(counts, offc, psum, zsum);
  transpose_all<<<dim3(24 * 512), 256, 0, stream>>>(Wg, Wu, Wd, WgT, WuT, WdT);
  router_kernel<<<dim3(T_TOK / 32), 256, 0, stream>>>(x, Wr, xb, topi, topw, counts, psum, zsum);
  finalize_kernel<<<1, 64, 0, stream>>>(counts, psum, zsum, bases, out + (size_t)T_TOK * Dm);
  scatter_kernel<<<dim3(T_TOK / 256), 256, 0, stream>>>(topi, topw, bases, offc, etok, ew);
  gemm_g_kernel<<<dim3(Fm / 128, 64, Em), 256, 0, stream>>>(xb, WgT, gh, etok, counts, bases);
  gemm_u_kernel<<<dim3(Fm / 128, 64, Em), 256, 0, stream>>>(xb, WuT, gh, etok, counts, bases);
  gemm2_kernel<<<dim3(Dm / 128, 64, Em), 256, 0, stream>>>(gh, WdT, out, etok, ew, counts, bases);
}

// Round 4
// 561.447 us; speedup vs baseline: 1.9182x; 1.1350x over previous
//
#include <hip/hip_runtime.h>
#include <cstdint>

#define T_TOK 8192
#define Dm 1024
#define Fm 2048
#define Em 8

typedef unsigned short u16;
typedef __attribute__((ext_vector_type(8))) short short8;   // 8 bf16 (4 VGPRs)
typedef __attribute__((ext_vector_type(4))) float floatx4;  // MFMA C/D

__device__ __forceinline__ u16 f2bf(float f) {
  union { float f; unsigned u; } v; v.f = f;
  unsigned r = v.u + 0x7fffu + ((v.u >> 16) & 1u);  // RNE
  return (u16)(r >> 16);
}

__device__ __forceinline__ void gld_lds16(const void* g, void* l) {
  __builtin_amdgcn_global_load_lds(
      (const __attribute__((address_space(1))) void*)g,
      (__attribute__((address_space(3))) void*)l, 16, 0, 0);
}

// ---------------- zero metadata ----------------
__global__ void zero_meta(int* counts, int* offc, float* psum, float* zsum) {
  int t = threadIdx.x;
  if (t < 8) { counts[t] = 0; offc[t] = 0; psum[t] = 0.f; }
  if (t == 8) zsum[0] = 0.f;
}

// ---------------- prep: weight transposes (blocks 0..12287) + router (blocks 12288..12543) ----------------
// Independent bandwidth-bound work fused into one launch to overlap.
__global__ __launch_bounds__(256) void prep_kernel(
    const float* __restrict__ Wg, const float* __restrict__ Wu, const float* __restrict__ Wd,
    u16* __restrict__ WgT, u16* __restrict__ WuT, u16* __restrict__ WdT,
    const float* __restrict__ x, const float* __restrict__ Wr, u16* __restrict__ xb,
    int* __restrict__ topi, float* __restrict__ topw,
    int* __restrict__ counts, float* __restrict__ psum, float* __restrict__ zsum) {
  __shared__ __align__(16) char smem[33056];
  int tid = threadIdx.x;
  if (blockIdx.x < 24 * 512) {
    // ---- transpose tile ----
    u16* tile = (u16*)smem;  // 64*66 u16 = 8448B
    int bid = blockIdx.x;
    int m = bid >> 9, t = bid & 511;
    int type = m >> 3, e = m & 7;
    const float* src; u16* dst; int R, C, csh;
    if (type == 0)      { src = Wg; dst = WgT; R = Dm; C = Fm; csh = 5; }
    else if (type == 1) { src = Wu; dst = WuT; R = Dm; C = Fm; csh = 5; }
    else                { src = Wd; dst = WdT; R = Fm; C = Dm; csh = 4; }
    int ty = t >> csh, tx = t & ((1 << csh) - 1);
    int r0 = ty * 64, c0 = tx * 64;
    const float* s = src + (size_t)e * R * C;
    u16* d = dst + (size_t)e * C * R;
#pragma unroll
    for (int p = 0; p < 16; ++p) {
      int idx = p * 256 + tid;
      int i = idx >> 6, j = idx & 63;
      tile[i * 66 + j] = f2bf(s[(size_t)(r0 + i) * C + (c0 + j)]);
    }
    __syncthreads();
#pragma unroll
    for (int p = 0; p < 16; ++p) {
      int idx = p * 256 + tid;
      int i = idx >> 6, j = idx & 63;
      d[(size_t)(c0 + i) * R + (r0 + j)] = tile[j * 66 + i];
    }
    return;
  }
  // ---- router block ----
  int rb = blockIdx.x - 24 * 512;  // 0..255
  float* wr_s = (float*)smem;                        // 32768 B
  float (*redf)[9] = (float(*)[9])(smem + 32768);    // 144 B
  int (*redi)[8] = (int(*)[8])(smem + 32768 + 144);  // 128 B
  for (int i = tid; i < Dm * Em; i += 256) wr_s[i] = Wr[i];
  __syncthreads();
  int wv = tid >> 6, lane = tid & 63;
  float pl[8] = {0, 0, 0, 0, 0, 0, 0, 0};
  float zl = 0.f;
  int cl[8] = {0, 0, 0, 0, 0, 0, 0, 0};
  for (int it = 0; it < 8; ++it) {
    int t = (rb * 4 + wv) * 8 + it;
    const float* xt = x + (size_t)t * Dm;
    u16* xbt = xb + (size_t)t * Dm;
    float acc[8] = {0, 0, 0, 0, 0, 0, 0, 0};
#pragma unroll
    for (int i = 0; i < 16; ++i) {
      int dd = i * 64 + lane;
      float xv = xt[dd];
      xbt[dd] = f2bf(xv);
#pragma unroll
      for (int e2 = 0; e2 < 8; ++e2) acc[e2] += xv * wr_s[dd * 8 + e2];
    }
#pragma unroll
    for (int e2 = 0; e2 < 8; ++e2) {
      float v = acc[e2];
      for (int o = 32; o > 0; o >>= 1) v += __shfl_down(v, o);
      acc[e2] = v;
    }
    if (lane == 0) {
      float m = acc[0];
#pragma unroll
      for (int e2 = 1; e2 < 8; ++e2) m = fmaxf(m, acc[e2]);
      float p[8]; float s = 0.f;
#pragma unroll
      for (int e2 = 0; e2 < 8; ++e2) { p[e2] = expf(acc[e2] - m); s += p[e2]; }
      float inv = 1.f / s;
#pragma unroll
      for (int e2 = 0; e2 < 8; ++e2) { p[e2] *= inv; pl[e2] += p[e2]; }
      float lse = m + logf(s);
      zl += lse * lse;
      int i1 = 0;
#pragma unroll
      for (int e2 = 1; e2 < 8; ++e2) if (p[e2] > p[i1]) i1 = e2;  // strict > : low idx wins ties
      int i2 = -1; float b2 = -1e30f;
#pragma unroll
      for (int e2 = 0; e2 < 8; ++e2)
        if (e2 != i1 && p[e2] > b2) { b2 = p[e2]; i2 = e2; }
      float ssum = p[i1] + p[i2];
      topi[2 * t] = i1; topi[2 * t + 1] = i2;
      topw[2 * t] = p[i1] / ssum; topw[2 * t + 1] = p[i2] / ssum;
      cl[i1]++; cl[i2]++;
    }
  }
  if (lane == 0) {
#pragma unroll
    for (int e2 = 0; e2 < 8; ++e2) { redf[wv][e2] = pl[e2]; redi[wv][e2] = cl[e2]; }
    redf[wv][8] = zl;
  }
  __syncthreads();
  if (tid < 8) {
    atomicAdd(&psum[tid], redf[0][tid] + redf[1][tid] + redf[2][tid] + redf[3][tid]);
    atomicAdd(&counts[tid], redi[0][tid] + redi[1][tid] + redi[2][tid] + redi[3][tid]);
  } else if (tid == 8) {
    atomicAdd(zsum, redf[0][8] + redf[1][8] + redf[2][8] + redf[3][8]);
  }
}

// ---------------- scatter: compact token lists per expert; inline bases; block0 writes aux ----------------
__global__ __launch_bounds__(256) void scatter_kernel(
    const int* __restrict__ topi, const float* __restrict__ topw,
    const int* __restrict__ counts, const float* __restrict__ psum, const float* __restrict__ zsum,
    int* __restrict__ offc, int* __restrict__ etok, float* __restrict__ ew,
    int* __restrict__ slots, float* __restrict__ out_aux) {
  __shared__ int lcnt[8];
  __shared__ int lbase[8];
  __shared__ int basesS[8];
  int tid = threadIdx.x;
  if (blockIdx.x == 0 && tid == 0) {
    float lb = 0.f;
    for (int e = 0; e < 8; ++e)
      lb += ((float)counts[e] / (2.f * T_TOK)) * (psum[e] / (float)T_TOK);
    lb *= 8.f;
    float z = zsum[0] / (float)T_TOK;
    *out_aux = 0.01f * lb + 0.001f * z;
  }
  if (tid < 8) {
    lcnt[tid] = 0;
    int b = 0;
    for (int e = 0; e < tid; ++e) b += counts[e];
    basesS[tid] = b;
  }
  __syncthreads();
  int t = blockIdx.x * 256 + tid;
  int e0 = topi[2 * t], e1 = topi[2 * t + 1];
  int lp0 = atomicAdd(&lcnt[e0], 1);
  int lp1 = atomicAdd(&lcnt[e1], 1);
  __syncthreads();
  if (tid < 8) lbase[tid] = atomicAdd(&offc[tid], lcnt[tid]);
  __syncthreads();
  int p0 = basesS[e0] + lbase[e0] + lp0;
  etok[p0] = t; ew[p0] = topw[2 * t]; slots[2 * t] = p0;
  int p1 = basesS[e1] + lbase[e1] + lp1;
  etok[p1] = t; ew[p1] = topw[2 * t + 1]; slots[2 * t + 1] = p1;
}

// ---------------- write bases to global for gemm kernels ----------------
__global__ void bases_kernel(const int* counts, int* bases) {
  if (threadIdx.x == 0) {
    int b = 0;
    for (int e = 0; e < 8; ++e) { bases[e] = b; b += counts[e]; }
  }
}

// ---------------- GEMM1 (fused): h = silu(X@Wg)*(X@Wu), gathered rows ----------------
// (256,2): round-2 showed (256,3) spills the 128-reg accumulator set -> 1.4GB scratch. Keep 2.
__global__ __launch_bounds__(256, 2) void gemm1_kernel(
    const u16* __restrict__ xb, const u16* __restrict__ WgT, const u16* __restrict__ WuT,
    u16* __restrict__ h, const int* __restrict__ etok,
    const int* __restrict__ counts, const int* __restrict__ bases) {
  const int e = blockIdx.z;
  const int Ne = counts[e];
  const int m0 = blockIdx.y * 128;
  if (m0 >= Ne) return;
  const int n0 = blockIdx.x * 128;
  const int be = bases[e];

  __shared__ __align__(16) u16 As[128 * 64];
  __shared__ __align__(16) u16 Bgs[128 * 64];
  __shared__ __align__(16) u16 Bus[128 * 64];

  const int tid = threadIdx.x;
  const int wv = tid >> 6, lane = tid & 63;
  const int wr = wv >> 1, wc = wv & 1;
  const int srow = tid >> 3;
  const int cg = (tid & 7) ^ (srow & 7);
  const u16* wg_e = WgT + (size_t)e * Fm * Dm;  // [F][D], k-contig
  const u16* wu_e = WuT + (size_t)e * Fm * Dm;

  const u16* ag[4]; const u16* bgp[4]; const u16* bup[4];
#pragma unroll
  for (int j = 0; j < 4; ++j) {
    int row = 32 * j + srow;
    int rr = m0 + row; rr = rr < Ne ? rr : Ne - 1;
    int tok = etok[be + rr];
    ag[j] = xb + (size_t)tok * Dm + cg * 8;
    bgp[j] = wg_e + (size_t)(n0 + row) * Dm + cg * 8;
    bup[j] = wu_e + (size_t)(n0 + row) * Dm + cg * 8;
  }
  const int lbase = 8 * wv * 64 + lane * 8;

  floatx4 accg[4][4], accu[4][4];
#pragma unroll
  for (int mi = 0; mi < 4; ++mi)
#pragma unroll
    for (int ni = 0; ni < 4; ++ni) { accg[mi][ni] = (floatx4)0.f; accu[mi][ni] = (floatx4)0.f; }

  for (int k0 = 0; k0 < Dm; k0 += 64) {
    __syncthreads();
#pragma unroll
    for (int j = 0; j < 4; ++j) {
      int lo = lbase + 32 * j * 64;
      gld_lds16(ag[j] + k0, &As[lo]);
      gld_lds16(bgp[j] + k0, &Bgs[lo]);
      gld_lds16(bup[j] + k0, &Bus[lo]);
    }
    __syncthreads();
#pragma unroll
    for (int ks = 0; ks < 2; ++ks) {
      short8 af[4], bgf[4], buf_[4];
      const int col = lane & 15, quad = lane >> 4;
      const int c = ks * 4 + quad;
#pragma unroll
      for (int mi = 0; mi < 4; ++mi) {
        int row = wr * 64 + mi * 16 + col;
        af[mi] = *(const short8*)&As[row * 64 + ((c ^ (row & 7)) << 3)];
      }
#pragma unroll
      for (int ni = 0; ni < 4; ++ni) {
        int row = wc * 64 + ni * 16 + col;
        int o = row * 64 + ((c ^ (row & 7)) << 3);
        bgf[ni] = *(const short8*)&Bgs[o];
        buf_[ni] = *(const short8*)&Bus[o];
      }
#pragma unroll
      for (int mi = 0; mi < 4; ++mi)
#pragma unroll
        for (int ni = 0; ni < 4; ++ni) {
          accg[mi][ni] = __builtin_amdgcn_mfma_f32_16x16x32_bf16(af[mi], bgf[ni], accg[mi][ni], 0, 0, 0);
          accu[mi][ni] = __builtin_amdgcn_mfma_f32_16x16x32_bf16(af[mi], buf_[ni], accu[mi][ni], 0, 0, 0);
        }
    }
  }
  const int col = lane & 15, quad = lane >> 4;
#pragma unroll
  for (int mi = 0; mi < 4; ++mi)
#pragma unroll
    for (int ni = 0; ni < 4; ++ni) {
      int f = n0 + wc * 64 + ni * 16 + col;
#pragma unroll
      for (int r = 0; r < 4; ++r) {
        int lrow = wr * 64 + mi * 16 + quad * 4 + r;
        if (m0 + lrow < Ne) {
          float gv = accg[mi][ni][r];
          float hv = (gv / (1.f + expf(-gv))) * accu[mi][ni][r];
          h[(size_t)(be + m0 + lrow) * Fm + f] = f2bf(hv);
        }
      }
    }
}

// ---------------- GEMM2: h2[slot] = w * (h @ Wd)  (plain stores, no atomics) ----------------
__global__ __launch_bounds__(256, 2) void gemm2_kernel(
    const u16* __restrict__ h, const u16* __restrict__ WdT, float* __restrict__ h2,
    const float* __restrict__ ew,
    const int* __restrict__ counts, const int* __restrict__ bases) {
  const int e = blockIdx.z;
  const int Ne = counts[e];
  const int m0 = blockIdx.y * 128;
  if (m0 >= Ne) return;
  const int n0 = blockIdx.x * 128;
  const int be = bases[e];

  __shared__ __align__(16) u16 As[128 * 64];
  __shared__ __align__(16) u16 Bs[128 * 64];
  __shared__ float wS[128];

  const int tid = threadIdx.x;
  if (tid < 128) {
    int rr = m0 + tid; rr = rr < Ne ? rr : Ne - 1;
    wS[tid] = ew[be + rr];
  }
  const int wv = tid >> 6, lane = tid & 63;
  const int wr = wv >> 1, wc = wv & 1;
  const int srow = tid >> 3;
  const int cg = (tid & 7) ^ (srow & 7);
  const u16* wd_e = WdT + (size_t)e * Dm * Fm;  // [D][F], k-contig

  const u16* ap[4]; const u16* bp[4];
#pragma unroll
  for (int j = 0; j < 4; ++j) {
    int row = 32 * j + srow;
    int rr = m0 + row; rr = rr < Ne ? rr : Ne - 1;
    ap[j] = h + (size_t)(be + rr) * Fm + cg * 8;
    bp[j] = wd_e + (size_t)(n0 + row) * Fm + cg * 8;
  }
  const int lbase = 8 * wv * 64 + lane * 8;

  floatx4 acc[4][4];
#pragma unroll
  for (int mi = 0; mi < 4; ++mi)
#pragma unroll
    for (int ni = 0; ni < 4; ++ni) acc[mi][ni] = (floatx4)0.f;

  for (int k0 = 0; k0 < Fm; k0 += 64) {
    __syncthreads();
#pragma unroll
    for (int j = 0; j < 4; ++j) {
      int lo = lbase + 32 * j * 64;
      gld_lds16(ap[j] + k0, &As[lo]);
      gld_lds16(bp[j] + k0, &Bs[lo]);
    }
    __syncthreads();
#pragma unroll
    for (int ks = 0; ks < 2; ++ks) {
      short8 af[4], bf[4];
      const int col = lane & 15, quad = lane >> 4;
      const int c = ks * 4 + quad;
#pragma unroll
      for (int mi = 0; mi < 4; ++mi) {
        int row = wr * 64 + mi * 16 + col;
        af[mi] = *(const short8*)&As[row * 64 + ((c ^ (row & 7)) << 3)];
      }
#pragma unroll
      for (int ni = 0; ni < 4; ++ni) {
        int row = wc * 64 + ni * 16 + col;
        bf[ni] = *(const short8*)&Bs[row * 64 + ((c ^ (row & 7)) << 3)];
      }
#pragma unroll
      for (int mi = 0; mi < 4; ++mi)
#pragma unroll
        for (int ni = 0; ni < 4; ++ni)
          acc[mi][ni] = __builtin_amdgcn_mfma_f32_16x16x32_bf16(af[mi], bf[ni], acc[mi][ni], 0, 0, 0);
    }
  }
  const int col = lane & 15, quad = lane >> 4;
#pragma unroll
  for (int mi = 0; mi < 4; ++mi)
#pragma unroll
    for (int ni = 0; ni < 4; ++ni) {
      int oc = n0 + wc * 64 + ni * 16 + col;
#pragma unroll
      for (int r = 0; r < 4; ++r) {
        int lrow = wr * 64 + mi * 16 + quad * 4 + r;
        if (m0 + lrow < Ne)
          h2[(size_t)(be + m0 + lrow) * Dm + oc] = acc[mi][ni][r] * wS[lrow];
      }
    }
}

// ---------------- combine: out[t] = h2[slot0[t]] + h2[slot1[t]] ----------------
__global__ __launch_bounds__(256) void combine_kernel(
    const float* __restrict__ h2, const int* __restrict__ slots, float* __restrict__ out) {
  int t = blockIdx.x;           // one block per token (256 threads x float4 = 1024 floats)
  int d4 = threadIdx.x;
  int s0 = slots[2 * t], s1 = slots[2 * t + 1];
  const float4* r0 = (const float4*)(h2 + (size_t)s0 * Dm);
  const float4* r1 = (const float4*)(h2 + (size_t)s1 * Dm);
  float4 a = r0[d4], b = r1[d4];
  float4 o = make_float4(a.x + b.x, a.y + b.y, a.z + b.z, a.w + b.w);
  ((float4*)(out + (size_t)t * Dm))[d4] = o;
}

extern "C" void kernel_launch(void* const* d_in, const int* in_sizes, int n_in,
                              void* d_out, int out_size, void* d_ws, size_t ws_size,
                              hipStream_t stream) {
  const float* x = (const float*)d_in[0];
  const float* Wr = (const float*)d_in[1];
  const float* Wg = (const float*)d_in[2];
  const float* Wu = (const float*)d_in[3];
  const float* Wd = (const float*)d_in[4];
  float* out = (float*)d_out;

  char* p = (char*)d_ws;
  auto take = [&](size_t bytes) { char* r = p; p += (bytes + 255) & ~(size_t)255; return r; };
  u16* WgT = (u16*)take((size_t)Em * Fm * Dm * 2);   // 33.5 MB  } h2 (67.1 MB fp32) aliases
  u16* WuT = (u16*)take((size_t)Em * Fm * Dm * 2);   // 33.5 MB  } these two after gemm1
  u16* WdT = (u16*)take((size_t)Em * Dm * Fm * 2);
  u16* xb = (u16*)take((size_t)T_TOK * Dm * 2);
  u16* gh = (u16*)take((size_t)2 * T_TOK * Fm * 2);
  int* topi = (int*)take((size_t)T_TOK * 2 * 4);
  float* topw = (float*)take((size_t)T_TOK * 2 * 4);
  int* etok = (int*)take((size_t)2 * T_TOK * 4);
  float* ew = (float*)take((size_t)2 * T_TOK * 4);
  int* slots = (int*)take((size_t)2 * T_TOK * 4);
  int* counts = (int*)take(64);
  int* bases = (int*)take(64);
  int* offc = (int*)take(64);
  float* psum = (float*)take(64);
  float* zsum = (float*)take(64);
  float* h2 = (float*)WgT;  // alias: WgT+WuT dead after gemm1; 2*T*D*4 == 2*(E*F*D*2)

  zero_meta<<<1, 64, 0, stream>>>(counts, offc, psum, zsum);
  prep_kernel<<<dim3(24 * 512 + 256), 256, 0, stream>>>(
      Wg, Wu, Wd, WgT, WuT, WdT, x, Wr, xb, topi, topw, counts, psum, zsum);
  scatter_kernel<<<dim3(T_TOK / 256), 256, 0, stream>>>(
      topi, topw, counts, psum, zsum, offc, etok, ew, slots, out + (size_t)T_TOK * Dm);
  bases_kernel<<<1, 64, 0, stream>>>(counts, bases);
  gemm1_kernel<<<dim3(Fm / 128, 64, Em), 256, 0, stream>>>(xb, WgT, WuT, gh, etok, counts, bases);
  gemm2_kernel<<<dim3(Dm / 128, 64, Em), 256, 0, stream>>>(gh, WdT, h2, ew, counts, bases);
  combine_kernel<<<dim3(T_TOK), 256, 0, stream>>>(h2, slots, out);
}

// Round 5
// 522.351 us; speedup vs baseline: 2.0618x; 1.0748x over previous
//
#include <hip/hip_runtime.h>
#include <cstdint>

#define T_TOK 8192
#define Dm 1024
#define Fm 2048
#define Em 8

typedef unsigned short u16;
typedef __attribute__((ext_vector_type(8))) short short8;   // 8 bf16 (4 VGPRs)
typedef __attribute__((ext_vector_type(4))) float floatx4;  // MFMA C/D

__device__ __forceinline__ u16 f2bf(float f) {
  union { float f; unsigned u; } v; v.f = f;
  unsigned r = v.u + 0x7fffu + ((v.u >> 16) & 1u);  // RNE
  return (u16)(r >> 16);
}

__device__ __forceinline__ void gld_lds16(const void* g, void* l) {
  __builtin_amdgcn_global_load_lds(
      (const __attribute__((address_space(1))) void*)g,
      (__attribute__((address_space(3))) void*)l, 16, 0, 0);
}

// ---------------- zero metadata ----------------
__global__ void zero_meta(int* counts, int* offc, float* psum, float* zsum) {
  int t = threadIdx.x;
  if (t < 8) { counts[t] = 0; offc[t] = 0; psum[t] = 0.f; }
  if (t == 8) zsum[0] = 0.f;
}

// ---------------- prep: router (blocks 0..255) + weight transposes (blocks 256..12543) ----------------
// Router first: it gates scatter->gemm1; transposes only gate gemm1's weight reads.
__global__ __launch_bounds__(256) void prep_kernel(
    const float* __restrict__ Wg, const float* __restrict__ Wu, const float* __restrict__ Wd,
    u16* __restrict__ WgT, u16* __restrict__ WuT, u16* __restrict__ WdT,
    const float* __restrict__ x, const float* __restrict__ Wr, u16* __restrict__ xb,
    int* __restrict__ topi, float* __restrict__ topw,
    int* __restrict__ counts, float* __restrict__ psum, float* __restrict__ zsum) {
  __shared__ __align__(16) char smem[33056];
  int tid = threadIdx.x;
  if (blockIdx.x >= 256) {
    // ---- transpose tile ----
    u16* tile = (u16*)smem;  // 64*66 u16 = 8448B
    int bid = blockIdx.x - 256;
    int m = bid >> 9, t = bid & 511;
    int type = m >> 3, e = m & 7;
    const float* src; u16* dst; int R, C, csh;
    if (type == 0)      { src = Wg; dst = WgT; R = Dm; C = Fm; csh = 5; }
    else if (type == 1) { src = Wu; dst = WuT; R = Dm; C = Fm; csh = 5; }
    else                { src = Wd; dst = WdT; R = Fm; C = Dm; csh = 4; }
    int ty = t >> csh, tx = t & ((1 << csh) - 1);
    int r0 = ty * 64, c0 = tx * 64;
    const float* s = src + (size_t)e * R * C;
    u16* d = dst + (size_t)e * C * R;
#pragma unroll
    for (int p = 0; p < 16; ++p) {
      int idx = p * 256 + tid;
      int i = idx >> 6, j = idx & 63;
      tile[i * 66 + j] = f2bf(s[(size_t)(r0 + i) * C + (c0 + j)]);
    }
    __syncthreads();
#pragma unroll
    for (int p = 0; p < 16; ++p) {
      int idx = p * 256 + tid;
      int i = idx >> 6, j = idx & 63;
      d[(size_t)(c0 + i) * R + (r0 + j)] = tile[j * 66 + i];
    }
    return;
  }
  // ---- router block ----
  int rb = blockIdx.x;  // 0..255
  float* wr_s = (float*)smem;                        // 32768 B
  float (*redf)[9] = (float(*)[9])(smem + 32768);    // 144 B
  int (*redi)[8] = (int(*)[8])(smem + 32768 + 144);  // 128 B
  for (int i = tid; i < Dm * Em; i += 256) wr_s[i] = Wr[i];
  __syncthreads();
  int wv = tid >> 6, lane = tid & 63;
  float pl[8] = {0, 0, 0, 0, 0, 0, 0, 0};
  float zl = 0.f;
  int cl[8] = {0, 0, 0, 0, 0, 0, 0, 0};
  for (int it = 0; it < 8; ++it) {
    int t = (rb * 4 + wv) * 8 + it;
    const float* xt = x + (size_t)t * Dm;
    u16* xbt = xb + (size_t)t * Dm;
    float acc[8] = {0, 0, 0, 0, 0, 0, 0, 0};
#pragma unroll
    for (int i = 0; i < 16; ++i) {
      int dd = i * 64 + lane;
      float xv = xt[dd];
      xbt[dd] = f2bf(xv);
#pragma unroll
      for (int e2 = 0; e2 < 8; ++e2) acc[e2] += xv * wr_s[dd * 8 + e2];
    }
#pragma unroll
    for (int e2 = 0; e2 < 8; ++e2) {
      float v = acc[e2];
      for (int o = 32; o > 0; o >>= 1) v += __shfl_down(v, o);
      acc[e2] = v;
    }
    if (lane == 0) {
      float m = acc[0];
#pragma unroll
      for (int e2 = 1; e2 < 8; ++e2) m = fmaxf(m, acc[e2]);
      float p[8]; float s = 0.f;
#pragma unroll
      for (int e2 = 0; e2 < 8; ++e2) { p[e2] = expf(acc[e2] - m); s += p[e2]; }
      float inv = 1.f / s;
#pragma unroll
      for (int e2 = 0; e2 < 8; ++e2) { p[e2] *= inv; pl[e2] += p[e2]; }
      float lse = m + logf(s);
      zl += lse * lse;
      int i1 = 0;
#pragma unroll
      for (int e2 = 1; e2 < 8; ++e2) if (p[e2] > p[i1]) i1 = e2;  // strict > : low idx wins ties
      int i2 = -1; float b2 = -1e30f;
#pragma unroll
      for (int e2 = 0; e2 < 8; ++e2)
        if (e2 != i1 && p[e2] > b2) { b2 = p[e2]; i2 = e2; }
      float ssum = p[i1] + p[i2];
      topi[2 * t] = i1; topi[2 * t + 1] = i2;
      topw[2 * t] = p[i1] / ssum; topw[2 * t + 1] = p[i2] / ssum;
      cl[i1]++; cl[i2]++;
    }
  }
  if (lane == 0) {
#pragma unroll
    for (int e2 = 0; e2 < 8; ++e2) { redf[wv][e2] = pl[e2]; redi[wv][e2] = cl[e2]; }
    redf[wv][8] = zl;
  }
  __syncthreads();
  if (tid < 8) {
    atomicAdd(&psum[tid], redf[0][tid] + redf[1][tid] + redf[2][tid] + redf[3][tid]);
    atomicAdd(&counts[tid], redi[0][tid] + redi[1][tid] + redi[2][tid] + redi[3][tid]);
  } else if (tid == 8) {
    atomicAdd(zsum, redf[0][8] + redf[1][8] + redf[2][8] + redf[3][8]);
  }
}

// ---------------- scatter: compaction + global bases + aux loss ----------------
__global__ __launch_bounds__(256) void scatter_kernel(
    const int* __restrict__ topi, const float* __restrict__ topw,
    const int* __restrict__ counts, const float* __restrict__ psum, const float* __restrict__ zsum,
    int* __restrict__ offc, int* __restrict__ etok, float* __restrict__ ew,
    int* __restrict__ slots, int* __restrict__ bases, float* __restrict__ out_aux) {
  __shared__ int lcnt[8];
  __shared__ int lbase[8];
  __shared__ int basesS[8];
  int tid = threadIdx.x;
  if (blockIdx.x == 0 && tid == 0) {
    float lb = 0.f;
    for (int e = 0; e < 8; ++e)
      lb += ((float)counts[e] / (2.f * T_TOK)) * (psum[e] / (float)T_TOK);
    lb *= 8.f;
    float z = zsum[0] / (float)T_TOK;
    *out_aux = 0.01f * lb + 0.001f * z;
  }
  if (tid < 8) {
    lcnt[tid] = 0;
    int b = 0;
    for (int e = 0; e < tid; ++e) b += counts[e];
    basesS[tid] = b;
    if (blockIdx.x == 0) bases[tid] = b;
  }
  __syncthreads();
  int t = blockIdx.x * 256 + tid;
  int e0 = topi[2 * t], e1 = topi[2 * t + 1];
  int lp0 = atomicAdd(&lcnt[e0], 1);
  int lp1 = atomicAdd(&lcnt[e1], 1);
  __syncthreads();
  if (tid < 8) lbase[tid] = atomicAdd(&offc[tid], lcnt[tid]);
  __syncthreads();
  int p0 = basesS[e0] + lbase[e0] + lp0;
  etok[p0] = t; ew[p0] = topw[2 * t]; slots[2 * t] = p0;
  int p1 = basesS[e1] + lbase[e1] + lp1;
  etok[p1] = t; ew[p1] = topw[2 * t + 1]; slots[2 * t + 1] = p1;
}

// ---------------- GEMM1 (fused, 128Mx64N tile): h = silu(X@Wg)*(X@Wu) ----------------
// 64-col N-tile: accg[4][2]+accu[4][2] = 64 acc regs -> total ~135 regs fits (256,3)'s 170 cap
// (no spill; round-2 showed 128-acc fused spills under any cap < ~240). LDS 32KB -> 3 blocks/CU.
__global__ __launch_bounds__(256, 3) void gemm1_kernel(
    const u16* __restrict__ xb, const u16* __restrict__ WgT, const u16* __restrict__ WuT,
    u16* __restrict__ h, const int* __restrict__ etok,
    const int* __restrict__ counts, const int* __restrict__ bases) {
  const int e = blockIdx.z;
  const int Ne = counts[e];
  const int m0 = blockIdx.y * 128;
  if (m0 >= Ne) return;
  const int n0 = blockIdx.x * 64;
  const int be = bases[e];

  __shared__ __align__(16) u16 As[128 * 64];   // 16KB
  __shared__ __align__(16) u16 Bgs[64 * 64];   // 8KB
  __shared__ __align__(16) u16 Bus[64 * 64];   // 8KB

  const int tid = threadIdx.x;
  const int wv = tid >> 6, lane = tid & 63;
  const int wr = wv >> 1, wc = wv & 1;       // wave covers rows wr*64..+64, cols wc*32..+32
  const int srow = tid >> 3;                 // 0..31
  const int cg = (tid & 7) ^ (srow & 7);     // xor-swizzled global chunk
  const u16* wg_e = WgT + (size_t)e * Fm * Dm;  // [F][D], k-contig
  const u16* wu_e = WuT + (size_t)e * Fm * Dm;

  const u16* ag[4]; const u16* bgp[2]; const u16* bup[2];
#pragma unroll
  for (int j = 0; j < 4; ++j) {
    int row = 32 * j + srow;
    int rr = m0 + row; rr = rr < Ne ? rr : Ne - 1;
    int tok = etok[be + rr];
    ag[j] = xb + (size_t)tok * Dm + cg * 8;
  }
#pragma unroll
  for (int j = 0; j < 2; ++j) {
    int row = 32 * j + srow;
    bgp[j] = wg_e + (size_t)(n0 + row) * Dm + cg * 8;
    bup[j] = wu_e + (size_t)(n0 + row) * Dm + cg * 8;
  }
  const int lbase = 8 * wv * 64 + lane * 8;  // forced lane layout (base + 16B*lane)

  floatx4 accg[4][2], accu[4][2];
#pragma unroll
  for (int mi = 0; mi < 4; ++mi)
#pragma unroll
    for (int ni = 0; ni < 2; ++ni) { accg[mi][ni] = (floatx4)0.f; accu[mi][ni] = (floatx4)0.f; }

  for (int k0 = 0; k0 < Dm; k0 += 64) {
    __syncthreads();
#pragma unroll
    for (int j = 0; j < 4; ++j) gld_lds16(ag[j] + k0, &As[lbase + 32 * j * 64]);
#pragma unroll
    for (int j = 0; j < 2; ++j) {
      int lo = lbase + 32 * j * 64;
      gld_lds16(bgp[j] + k0, &Bgs[lo]);
      gld_lds16(bup[j] + k0, &Bus[lo]);
    }
    __syncthreads();
#pragma unroll
    for (int ks = 0; ks < 2; ++ks) {
      short8 af[4], bgf[2], buf_[2];
      const int col = lane & 15, quad = lane >> 4;
      const int c = ks * 4 + quad;
#pragma unroll
      for (int mi = 0; mi < 4; ++mi) {
        int row = wr * 64 + mi * 16 + col;
        af[mi] = *(const short8*)&As[row * 64 + ((c ^ (row & 7)) << 3)];
      }
#pragma unroll
      for (int ni = 0; ni < 2; ++ni) {
        int row = wc * 32 + ni * 16 + col;
        int o = row * 64 + ((c ^ (row & 7)) << 3);
        bgf[ni] = *(const short8*)&Bgs[o];
        buf_[ni] = *(const short8*)&Bus[o];
      }
#pragma unroll
      for (int mi = 0; mi < 4; ++mi)
#pragma unroll
        for (int ni = 0; ni < 2; ++ni) {
          accg[mi][ni] = __builtin_amdgcn_mfma_f32_16x16x32_bf16(af[mi], bgf[ni], accg[mi][ni], 0, 0, 0);
          accu[mi][ni] = __builtin_amdgcn_mfma_f32_16x16x32_bf16(af[mi], buf_[ni], accu[mi][ni], 0, 0, 0);
        }
    }
  }
  const int col = lane & 15, quad = lane >> 4;
#pragma unroll
  for (int mi = 0; mi < 4; ++mi)
#pragma unroll
    for (int ni = 0; ni < 2; ++ni) {
      int f = n0 + wc * 32 + ni * 16 + col;
#pragma unroll
      for (int r = 0; r < 4; ++r) {
        int lrow = wr * 64 + mi * 16 + quad * 4 + r;
        if (m0 + lrow < Ne) {
          float gv = accg[mi][ni][r];
          float hv = (gv / (1.f + expf(-gv))) * accu[mi][ni][r];
          h[(size_t)(be + m0 + lrow) * Fm + f] = f2bf(hv);
        }
      }
    }
}

// ---------------- GEMM2 (128Mx64N tile): h2[slot] = w * (h @ Wd), plain stores ----------------
__global__ __launch_bounds__(256, 3) void gemm2_kernel(
    const u16* __restrict__ h, const u16* __restrict__ WdT, float* __restrict__ h2,
    const float* __restrict__ ew,
    const int* __restrict__ counts, const int* __restrict__ bases) {
  const int e = blockIdx.z;
  const int Ne = counts[e];
  const int m0 = blockIdx.y * 128;
  if (m0 >= Ne) return;
  const int n0 = blockIdx.x * 64;
  const int be = bases[e];

  __shared__ __align__(16) u16 As[128 * 64];  // 16KB
  __shared__ __align__(16) u16 Bs[64 * 64];   // 8KB
  __shared__ float wS[128];

  const int tid = threadIdx.x;
  if (tid < 128) {
    int rr = m0 + tid; rr = rr < Ne ? rr : Ne - 1;
    wS[tid] = ew[be + rr];
  }
  const int wv = tid >> 6, lane = tid & 63;
  const int wr = wv >> 1, wc = wv & 1;
  const int srow = tid >> 3;
  const int cg = (tid & 7) ^ (srow & 7);
  const u16* wd_e = WdT + (size_t)e * Dm * Fm;  // [D][F], k-contig

  const u16* ap[4]; const u16* bp[2];
#pragma unroll
  for (int j = 0; j < 4; ++j) {
    int row = 32 * j + srow;
    int rr = m0 + row; rr = rr < Ne ? rr : Ne - 1;
    ap[j] = h + (size_t)(be + rr) * Fm + cg * 8;
  }
#pragma unroll
  for (int j = 0; j < 2; ++j) {
    int row = 32 * j + srow;
    bp[j] = wd_e + (size_t)(n0 + row) * Fm + cg * 8;
  }
  const int lbase = 8 * wv * 64 + lane * 8;

  floatx4 acc[4][2];
#pragma unroll
  for (int mi = 0; mi < 4; ++mi)
#pragma unroll
    for (int ni = 0; ni < 2; ++ni) acc[mi][ni] = (floatx4)0.f;

  for (int k0 = 0; k0 < Fm; k0 += 64) {
    __syncthreads();
#pragma unroll
    for (int j = 0; j < 4; ++j) gld_lds16(ap[j] + k0, &As[lbase + 32 * j * 64]);
#pragma unroll
    for (int j = 0; j < 2; ++j) gld_lds16(bp[j] + k0, &Bs[lbase + 32 * j * 64]);
    __syncthreads();
#pragma unroll
    for (int ks = 0; ks < 2; ++ks) {
      short8 af[4], bf[2];
      const int col = lane & 15, quad = lane >> 4;
      const int c = ks * 4 + quad;
#pragma unroll
      for (int mi = 0; mi < 4; ++mi) {
        int row = wr * 64 + mi * 16 + col;
        af[mi] = *(const short8*)&As[row * 64 + ((c ^ (row & 7)) << 3)];
      }
#pragma unroll
      for (int ni = 0; ni < 2; ++ni) {
        int row = wc * 32 + ni * 16 + col;
        bf[ni] = *(const short8*)&Bs[row * 64 + ((c ^ (row & 7)) << 3)];
      }
#pragma unroll
      for (int mi = 0; mi < 4; ++mi)
#pragma unroll
        for (int ni = 0; ni < 2; ++ni)
          acc[mi][ni] = __builtin_amdgcn_mfma_f32_16x16x32_bf16(af[mi], bf[ni], acc[mi][ni], 0, 0, 0);
    }
  }
  const int col = lane & 15, quad = lane >> 4;
#pragma unroll
  for (int mi = 0; mi < 4; ++mi)
#pragma unroll
    for (int ni = 0; ni < 2; ++ni) {
      int oc = n0 + wc * 32 + ni * 16 + col;
#pragma unroll
      for (int r = 0; r < 4; ++r) {
        int lrow = wr * 64 + mi * 16 + quad * 4 + r;
        if (m0 + lrow < Ne)
          h2[(size_t)(be + m0 + lrow) * Dm + oc] = acc[mi][ni][r] * wS[lrow];
      }
    }
}

// ---------------- combine: out[t] = h2[slot0[t]] + h2[slot1[t]] ----------------
__global__ __launch_bounds__(256) void combine_kernel(
    const float* __restrict__ h2, const int* __restrict__ slots, float* __restrict__ out) {
  int t = blockIdx.x;
  int d4 = threadIdx.x;
  int s0 = slots[2 * t], s1 = slots[2 * t + 1];
  const float4* r0 = (const float4*)(h2 + (size_t)s0 * Dm);
  const float4* r1 = (const float4*)(h2 + (size_t)s1 * Dm);
  float4 a = r0[d4], b = r1[d4];
  float4 o = make_float4(a.x + b.x, a.y + b.y, a.z + b.z, a.w + b.w);
  ((float4*)(out + (size_t)t * Dm))[d4] = o;
}

extern "C" void kernel_launch(void* const* d_in, const int* in_sizes, int n_in,
                              void* d_out, int out_size, void* d_ws, size_t ws_size,
                              hipStream_t stream) {
  const float* x = (const float*)d_in[0];
  const float* Wr = (const float*)d_in[1];
  const float* Wg = (const float*)d_in[2];
  const float* Wu = (const float*)d_in[3];
  const float* Wd = (const float*)d_in[4];
  float* out = (float*)d_out;

  char* p = (char*)d_ws;
  auto take = [&](size_t bytes) { char* r = p; p += (bytes + 255) & ~(size_t)255; return r; };
  u16* WgT = (u16*)take((size_t)Em * Fm * Dm * 2);   // 33.5 MB  } h2 (67.1 MB fp32) aliases
  u16* WuT = (u16*)take((size_t)Em * Fm * Dm * 2);   // 33.5 MB  } these two after gemm1
  u16* WdT = (u16*)take((size_t)Em * Dm * Fm * 2);
  u16* xb = (u16*)take((size_t)T_TOK * Dm * 2);
  u16* gh = (u16*)take((size_t)2 * T_TOK * Fm * 2);
  int* topi = (int*)take((size_t)T_TOK * 2 * 4);
  float* topw = (float*)take((size_t)T_TOK * 2 * 4);
  int* etok = (int*)take((size_t)2 * T_TOK * 4);
  float* ew = (float*)take((size_t)2 * T_TOK * 4);
  int* slots = (int*)take((size_t)2 * T_TOK * 4);
  int* counts = (int*)take(64);
  int* bases = (int*)take(64);
  int* offc = (int*)take(64);
  float* psum = (float*)take(64);
  float* zsum = (float*)take(64);
  float* h2 = (float*)WgT;  // alias: WgT+WuT dead after gemm1; 2*T*D*4 == 2*(E*F*D*2)

  zero_meta<<<1, 64, 0, stream>>>(counts, offc, psum, zsum);
  prep_kernel<<<dim3(24 * 512 + 256), 256, 0, stream>>>(
      Wg, Wu, Wd, WgT, WuT, WdT, x, Wr, xb, topi, topw, counts, psum, zsum);
  scatter_kernel<<<dim3(T_TOK / 256), 256, 0, stream>>>(
      topi, topw, counts, psum, zsum, offc, etok, ew, slots, bases, out + (size_t)T_TOK * Dm);
  gemm1_kernel<<<dim3(Fm / 64, 64, Em), 256, 0, stream>>>(xb, WgT, WuT, gh, etok, counts, bases);
  gemm2_kernel<<<dim3(Dm / 64, 64, Em), 256, 0, stream>>>(gh, WdT, h2, ew, counts, bases);
  combine_kernel<<<dim3(T_TOK), 256, 0, stream>>>(h2, slots, out);
}